// Round 1
// baseline (7069.788 us; speedup 1.0000x reference)
//
#include <hip/hip_runtime.h>
#include <math.h>

// Decoder: B=64, T=32, S=64, V=32000, E=512, H=1024
// Strategy:
//   Phase A (parallel): xk = emb[tokens] @ k0[:E] + b0  (all T at once, teacher forcing)
//                       keys = memory @ Wk
//   Phase B (32 sequential steps): split-K fp32 GEMMs -> partials, fused LSTM /
//                       softmax+ctx / reduce epilogues. attn(t) stored into outs[:,t,:].
//   Phase C: logits = outs @ Wfc + bfc
// All fp32 (no fp32-input MFMA on CDNA4 -> vector FMA; bf16 MFMA is a later round
// once verification tolerance is known).

#define Bsz 64
#define Tsz 32
#define Ssz 64
#define Vsz 32000
#define Esz 512
#define Hsz 1024

__device__ __forceinline__ float sigm(float x) { return 1.0f / (1.0f + __expf(-x)); }

// ---------------------------------------------------------------------------
// Generic tiled fp32 GEMM: C[m,n] = sum_k A[row(m),k]*W[k,n] (+bias[n])
// BM=128 always. Thread-tile TM x TN(=8). b-frag split as two float4 at
// tx*4 and BN/2+tx*4 so LDS reads are consecutive-16B (conflict-free).
// ---------------------------------------------------------------------------
template <int BM, int BN, int TM, int TN>
__global__ __launch_bounds__(256) void gemm_t(
    const float* __restrict__ A, const float* __restrict__ W,
    const float* __restrict__ bias, const int* __restrict__ gather,
    float* __restrict__ C, int M, int N, int K, int lda)
{
    static_assert(BM == 128 && TN == 8, "cfg");
    constexpr int THRN = BN / TN;  // 32 (cfgA) / 16 (cfgB)
    __shared__ float As[16][BM];
    __shared__ float Bs[16][BN];

    const int t  = threadIdx.x;
    const int bm = blockIdx.x * BM;
    const int bn = blockIdx.y * BN;
    const int tx = t % THRN;
    const int ty = t / THRN;

    float acc[TM][TN];
#pragma unroll
    for (int i = 0; i < TM; ++i)
#pragma unroll
        for (int j = 0; j < TN; ++j) acc[i][j] = 0.0f;

    // A staging: 128 rows x 16 k, 2 float4 per thread
    const int am = t >> 1;
    const int ak = (t & 1) * 8;
    const int arow = gather ? gather[bm + am] : (bm + am);
    const float* Ap = A + (size_t)arow * lda + ak;

    for (int k0 = 0; k0 < K; k0 += 16) {
        float4 a0 = *(const float4*)(Ap + k0);
        float4 a1 = *(const float4*)(Ap + k0 + 4);
        As[ak + 0][am] = a0.x; As[ak + 1][am] = a0.y;
        As[ak + 2][am] = a0.z; As[ak + 3][am] = a0.w;
        As[ak + 4][am] = a1.x; As[ak + 5][am] = a1.y;
        As[ak + 6][am] = a1.z; As[ak + 7][am] = a1.w;
#pragma unroll
        for (int j = 0; j < BN / 64; ++j) {
            int flat = t + 256 * j;
            int kk = flat / (BN / 4);
            int n4 = (flat % (BN / 4)) * 4;
            *(float4*)&Bs[kk][n4] =
                *(const float4*)(W + (size_t)(k0 + kk) * N + bn + n4);
        }
        __syncthreads();
#pragma unroll
        for (int k = 0; k < 16; ++k) {
            float a[TM], b[TN];
#pragma unroll
            for (int i = 0; i < TM / 4; ++i)
                *(float4*)&a[i * 4] = *(const float4*)&As[k][ty * TM + i * 4];
            *(float4*)&b[0] = *(const float4*)&Bs[k][tx * 4];
            *(float4*)&b[4] = *(const float4*)&Bs[k][BN / 2 + tx * 4];
#pragma unroll
            for (int i = 0; i < TM; ++i)
#pragma unroll
                for (int j = 0; j < TN; ++j) acc[i][j] += a[i] * b[j];
        }
        __syncthreads();
    }

    float bv[8] = {0, 0, 0, 0, 0, 0, 0, 0};
    if (bias) {
#pragma unroll
        for (int j = 0; j < 4; ++j) {
            bv[j]     = bias[bn + tx * 4 + j];
            bv[4 + j] = bias[bn + BN / 2 + tx * 4 + j];
        }
    }
#pragma unroll
    for (int i = 0; i < TM; ++i) {
        int row = bm + ty * TM + i;
        float4 o0 = make_float4(acc[i][0] + bv[0], acc[i][1] + bv[1],
                                acc[i][2] + bv[2], acc[i][3] + bv[3]);
        float4 o1 = make_float4(acc[i][4] + bv[4], acc[i][5] + bv[5],
                                acc[i][6] + bv[6], acc[i][7] + bv[7]);
        *(float4*)(C + (size_t)row * N + bn + tx * 4) = o0;
        *(float4*)(C + (size_t)row * N + bn + BN / 2 + tx * 4) = o1;
    }
}

// ---------------------------------------------------------------------------
// Split-K skinny GEMM (M=64): partial[p][64][Ntot tile] over a 64-wide K slice.
// Slices 0..15 use (A1,W1) with koff=p*64; 16..31 use (A2,W2), koff=(p-16)*64.
// Tile 64x256, thread-tile 8x8.
// ---------------------------------------------------------------------------
__global__ __launch_bounds__(256) void bgemm(
    const float* __restrict__ A1, int lda1,
    const float* __restrict__ A2, int lda2,
    const float* __restrict__ W1, const float* __restrict__ W2, int ldw,
    float* __restrict__ part, int Ntot, int p_off)
{
    __shared__ float As[16][64];
    __shared__ float Ws[16][256];

    const int t  = threadIdx.x;
    const int bn = blockIdx.x * 256;
    const int p  = blockIdx.y + p_off;

    const float* A; const float* W; int lda; int koff;
    if (p < 16) { A = A1; lda = lda1; W = W1; koff = p * 64; }
    else        { A = A2; lda = lda2; W = W2; koff = (p - 16) * 64; }

    const int tx = t & 31;
    const int ty = t >> 5;

    float acc[8][8];
#pragma unroll
    for (int i = 0; i < 8; ++i)
#pragma unroll
        for (int j = 0; j < 8; ++j) acc[i][j] = 0.0f;

    const int am = t >> 2;
    const int ak = (t & 3) * 4;
    const float* Ap = A + (size_t)am * lda + koff + ak;

    for (int kc = 0; kc < 64; kc += 16) {
        float4 av = *(const float4*)(Ap + kc);
        As[ak + 0][am] = av.x; As[ak + 1][am] = av.y;
        As[ak + 2][am] = av.z; As[ak + 3][am] = av.w;
#pragma unroll
        for (int j = 0; j < 4; ++j) {
            int flat = t + 256 * j;
            int kk = flat >> 6;
            int n4 = (flat & 63) * 4;
            *(float4*)&Ws[kk][n4] =
                *(const float4*)(W + (size_t)(koff + kc + kk) * ldw + bn + n4);
        }
        __syncthreads();
#pragma unroll
        for (int k = 0; k < 16; ++k) {
            float a[8], b[8];
            *(float4*)&a[0] = *(const float4*)&As[k][ty * 8];
            *(float4*)&a[4] = *(const float4*)&As[k][ty * 8 + 4];
            *(float4*)&b[0] = *(const float4*)&Ws[k][tx * 4];
            *(float4*)&b[4] = *(const float4*)&Ws[k][128 + tx * 4];
#pragma unroll
            for (int i = 0; i < 8; ++i)
#pragma unroll
                for (int j = 0; j < 8; ++j) acc[i][j] += a[i] * b[j];
        }
        __syncthreads();
    }

    float* outp = part + (size_t)p * 64 * Ntot + bn;
#pragma unroll
    for (int i = 0; i < 8; ++i) {
        int row = ty * 8 + i;
        *(float4*)(outp + (size_t)row * Ntot + tx * 4) =
            make_float4(acc[i][0], acc[i][1], acc[i][2], acc[i][3]);
        *(float4*)(outp + (size_t)row * Ntot + 128 + tx * 4) =
            make_float4(acc[i][4], acc[i][5], acc[i][6], acc[i][7]);
    }
}

// ---------------------------------------------------------------------------
// Reduce gate partials + optional additive term (xk slice) + bias, LSTM update.
// 65536 threads: (b,h). Gate cols = g*1024 + h, TF order i,f,g,o.
// ---------------------------------------------------------------------------
__global__ __launch_bounds__(256) void lstm_k(
    const float* __restrict__ part, int pbase,
    const float* __restrict__ addin, int adstride,
    const float* __restrict__ bias,
    const float* __restrict__ cin, float* __restrict__ cout,
    float* __restrict__ hout)
{
    int idx = blockIdx.x * 256 + threadIdx.x;  // 0..65535
    int b = idx >> 10;
    int h = idx & 1023;
    float zi = 0, zf = 0, zg = 0, zo = 0;
    for (int p = pbase; p < 32; ++p) {
        const float* q = part + (size_t)p * 64 * 4096 + b * 4096 + h;
        zi += q[0]; zf += q[1024]; zg += q[2048]; zo += q[3072];
    }
    if (addin) {
        const float* a = addin + (size_t)b * adstride + h;
        zi += a[0]; zf += a[1024]; zg += a[2048]; zo += a[3072];
    }
    if (bias) {
        zi += bias[h]; zf += bias[1024 + h];
        zg += bias[2048 + h]; zo += bias[3072 + h];
    }
    float cc = sigm(zf) * cin[idx] + sigm(zi) * tanhf(zg);
    cout[idx] = cc;
    hout[idx] = sigm(zo) * tanhf(cc);
}

// ---------------------------------------------------------------------------
// Per-b block: reduce q partials, Bahdanau scores, softmax over S, ctx.
// ---------------------------------------------------------------------------
__global__ __launch_bounds__(256) void attn_k(
    const float* __restrict__ qpart, const float* __restrict__ keys,
    const float* __restrict__ vvec, const float* __restrict__ mem,
    float* __restrict__ ctx)
{
    __shared__ float q_lds[1024];
    __shared__ float v_lds[1024];
    __shared__ float s_lds[64];
    const int b = blockIdx.x;
    const int t = threadIdx.x;

#pragma unroll
    for (int j = 0; j < 4; ++j) {
        int u = t + 256 * j;
        float acc = 0;
#pragma unroll
        for (int p = 0; p < 16; ++p) acc += qpart[(size_t)p * 65536 + b * 1024 + u];
        q_lds[u] = acc;
        v_lds[u] = vvec[u];
    }
    __syncthreads();

    // scores: 4 lanes per s, interleaved float4 over u
    const int s = t >> 2;
    const int uq = t & 3;
    const float* krow = keys + (size_t)b * (Ssz * Hsz) + s * Hsz;
    float sc = 0;
    for (int i = 0; i < 64; ++i) {
        int u = i * 16 + uq * 4;
        float4 kv = *(const float4*)(krow + u);
        sc += v_lds[u + 0] * tanhf(kv.x + q_lds[u + 0]);
        sc += v_lds[u + 1] * tanhf(kv.y + q_lds[u + 1]);
        sc += v_lds[u + 2] * tanhf(kv.z + q_lds[u + 2]);
        sc += v_lds[u + 3] * tanhf(kv.w + q_lds[u + 3]);
    }
    sc += __shfl_xor(sc, 1);
    sc += __shfl_xor(sc, 2);
    if (uq == 0) s_lds[s] = sc;
    __syncthreads();

    if (t < 64) {  // one full wave does the 64-wide softmax
        float x = s_lds[t];
        float mx = x;
        for (int d = 1; d < 64; d <<= 1) mx = fmaxf(mx, __shfl_xor(mx, d));
        float e = __expf(x - mx);
        float sm = e;
        for (int d = 1; d < 64; d <<= 1) sm += __shfl_xor(sm, d);
        s_lds[t] = e / sm;
    }
    __syncthreads();

#pragma unroll
    for (int j = 0; j < 4; ++j) {
        int m = t + 256 * j;
        float acc = 0;
        for (int s2 = 0; s2 < 64; ++s2)
            acc += s_lds[s2] * mem[(size_t)b * (Ssz * Hsz) + s2 * Hsz + m];
        ctx[b * 1024 + m] = acc;
    }
}

// Sum 32 attn-proj partials -> outs[:, tstep, :]
__global__ __launch_bounds__(256) void radd(
    const float* __restrict__ part, float* __restrict__ outs, int tstep)
{
    int idx = blockIdx.x * 256 + threadIdx.x;  // 0..65535
    int b = idx >> 10;
    int n = idx & 1023;
    float acc = 0;
#pragma unroll
    for (int p = 0; p < 32; ++p) acc += part[(size_t)p * 65536 + idx];
    outs[((size_t)b * Tsz + tstep) * Hsz + n] = acc;
}

// ---------------------------------------------------------------------------
extern "C" void kernel_launch(void* const* d_in, const int* in_sizes, int n_in,
                              void* d_out, int out_size, void* d_ws, size_t ws_size,
                              hipStream_t stream)
{
    (void)in_sizes; (void)n_in; (void)out_size; (void)ws_size;
    const int*   tokens = (const int*)  d_in[0];
    const float* memory = (const float*)d_in[1];
    const float* enc_h  = (const float*)d_in[2];
    const float* enc_c  = (const float*)d_in[3];
    const float* emb    = (const float*)d_in[4];
    const float* k0     = (const float*)d_in[5];
    const float* r0     = (const float*)d_in[6];
    const float* b0     = (const float*)d_in[7];
    const float* k1     = (const float*)d_in[8];
    const float* r1     = (const float*)d_in[9];
    const float* b1     = (const float*)d_in[10];
    const float* Wq     = (const float*)d_in[11];
    const float* Wk     = (const float*)d_in[12];
    const float* vvec   = (const float*)d_in[13];
    const float* Wa     = (const float*)d_in[14];
    const float* Wfc    = (const float*)d_in[15];
    const float* bfc    = (const float*)d_in[16];
    float* out = (float*)d_out;

    float* w    = (float*)d_ws;
    float* xk   = w; w += (size_t)2048 * 4096;   // [B*T, 4H]
    float* keys = w; w += (size_t)4096 * 1024;   // [B*S, H]
    float* outs = w; w += (size_t)2048 * 1024;   // [B, T, H] attn outputs
    float* h0   = w; w += 65536;
    float* c0   = w; w += 65536;
    float* h1   = w; w += 65536;
    float* c1   = w; w += 65536;
    float* gp   = w; w += (size_t)32 * 64 * 4096;  // gate partials (shared B1/B2)
    float* qp   = w; w += (size_t)16 * 65536;      // q partials
    float* ap   = w; w += (size_t)32 * 65536;      // attn-proj partials
    float* ctxb = w; w += 65536;

    // Phase A: xk = emb[tokens] @ k0[0:E] + b0 ;  keys = memory @ Wk
    gemm_t<128, 256, 16, 8><<<dim3(16, 16), 256, 0, stream>>>(
        emb, k0, b0, tokens, xk, 2048, 4096, Esz, Esz);
    gemm_t<128, 128, 8, 8><<<dim3(32, 8), 256, 0, stream>>>(
        memory, Wk, nullptr, nullptr, keys, 4096, 1024, 1024, 1024);

    const float* k0a = k0 + (size_t)Esz * 4096;  // attn-input rows of k0

    for (int t = 0; t < Tsz; ++t) {
        const float* a_prev = outs + (size_t)(t - 1) * Hsz;  // row stride T*H
        const float* h0_in = (t == 0) ? enc_h : h0;
        const float* h1_in = (t == 0) ? enc_h : h1;
        const float* c0_in = (t == 0) ? enc_c : c0;
        const float* c1_in = (t == 0) ? enc_c : c1;

        // gates0 partials: [attn_prev | h0] @ [k0a ; r0]  (t=0: attn=0 -> h0 side only)
        if (t == 0)
            bgemm<<<dim3(16, 16), 256, 0, stream>>>(
                nullptr, 0, h0_in, 1024, k0a, r0, 4096, gp, 4096, 16);
        else
            bgemm<<<dim3(16, 32), 256, 0, stream>>>(
                a_prev, Tsz * Hsz, h0_in, 1024, k0a, r0, 4096, gp, 4096, 0);
        // LSTM0 (b0 already folded into xk)
        lstm_k<<<256, 256, 0, stream>>>(
            gp, (t == 0) ? 16 : 0, xk + (size_t)t * 4096, Tsz * 4096,
            nullptr, c0_in, c0, h0);
        // gates1 partials: [h0 | h1] @ [k1 ; r1]
        bgemm<<<dim3(16, 32), 256, 0, stream>>>(
            h0, 1024, h1_in, 1024, k1, r1, 4096, gp, 4096, 0);
        lstm_k<<<256, 256, 0, stream>>>(
            gp, 0, nullptr, 0, b1, c1_in, c1, h1);
        // q partials: h1 @ Wq
        bgemm<<<dim3(4, 16), 256, 0, stream>>>(
            h1, 1024, nullptr, 0, Wq, nullptr, 1024, qp, 1024, 0);
        // scores + softmax + ctx
        attn_k<<<64, 256, 0, stream>>>(qp, keys, vvec, memory, ctxb);
        // attn-proj partials: [h1 | ctx] @ Wa
        bgemm<<<dim3(4, 32), 256, 0, stream>>>(
            h1, 1024, ctxb, 1024, Wa, Wa + (size_t)1024 * 1024, 1024, ap, 1024, 0);
        // reduce -> outs[:, t, :]
        radd<<<256, 256, 0, stream>>>(ap, outs, t);
    }

    // Phase C: logits = outs @ Wfc + bfc
    gemm_t<128, 256, 16, 8><<<dim3(16, 125), 256, 0, stream>>>(
        outs, Wfc, bfc, nullptr, out, 2048, Vsz, 1024, 1024);
}

// Round 5
// 6640.343 us; speedup vs baseline: 1.0647x; 1.0647x over previous
//
#include <hip/hip_runtime.h>
#include <hip/hip_bf16.h>
#include <math.h>

// Decoder: B=64, T=32, S=64, V=32000, E=512, H=1024
// Phase A (parallel): xk = emb[tokens] @ k0[:E] + b0 ; keys = memory @ Wk
// Phase B (32 sequential steps): split-K fp32 GEMMs (16 slices x K=128) +
//   fused LSTM / attn / reduce. radd emits bf16 hi/lo splits of outs.
// Phase C: logits = outs @ Wfc + bfc via split-bf16 3-pass MFMA
//   (Ahi@Whi + Alo@Whi + Ahi@Wlo), 32x32x16 bf16 MFMA, fp32 accum.
// Staging in mfmaC_k is REGISTER-staged (global_load_dwordx4 + ds_write_b128)
//   -- the instruction class proven safe in round-1's passing kernels;
//   global_load_lds deferred to an isolated A/B once a baseline passes.
// Workspace: phase-C scratch overlays phase-AB scratch; total ~88 MB
//   (round-1's ~106 MB passed, so ws_size >= that).

#define Bsz 64
#define Tsz 32
#define Ssz 64
#define Vsz 32000
#define Esz 512
#define Hsz 1024

typedef short bhalf8 __attribute__((ext_vector_type(8)));
typedef float floatx16 __attribute__((ext_vector_type(16)));

__device__ __forceinline__ float sigm(float x) { return 1.0f / (1.0f + __expf(-x)); }

// ---------------------------------------------------------------------------
// Generic tiled fp32 GEMM (phase A): C[m,n] = sum_k A[row(m),k]*W[k,n] (+bias)
// ---------------------------------------------------------------------------
template <int BM, int BN, int TM, int TN>
__global__ __launch_bounds__(256) void gemm_t(
    const float* __restrict__ A, const float* __restrict__ W,
    const float* __restrict__ bias, const int* __restrict__ gather,
    float* __restrict__ C, int M, int N, int K, int lda)
{
    static_assert(BM == 128 && TN == 8, "cfg");
    constexpr int THRN = BN / TN;
    __shared__ float As[16][BM];
    __shared__ float Bs[16][BN];

    const int t  = threadIdx.x;
    const int bm = blockIdx.x * BM;
    const int bn = blockIdx.y * BN;
    const int tx = t % THRN;
    const int ty = t / THRN;

    float acc[TM][TN];
#pragma unroll
    for (int i = 0; i < TM; ++i)
#pragma unroll
        for (int j = 0; j < TN; ++j) acc[i][j] = 0.0f;

    const int am = t >> 1;
    const int ak = (t & 1) * 8;
    const int arow = gather ? gather[bm + am] : (bm + am);
    const float* Ap = A + (size_t)arow * lda + ak;

    for (int k0 = 0; k0 < K; k0 += 16) {
        float4 a0 = *(const float4*)(Ap + k0);
        float4 a1 = *(const float4*)(Ap + k0 + 4);
        As[ak + 0][am] = a0.x; As[ak + 1][am] = a0.y;
        As[ak + 2][am] = a0.z; As[ak + 3][am] = a0.w;
        As[ak + 4][am] = a1.x; As[ak + 5][am] = a1.y;
        As[ak + 6][am] = a1.z; As[ak + 7][am] = a1.w;
#pragma unroll
        for (int j = 0; j < BN / 64; ++j) {
            int flat = t + 256 * j;
            int kk = flat / (BN / 4);
            int n4 = (flat % (BN / 4)) * 4;
            *(float4*)&Bs[kk][n4] =
                *(const float4*)(W + (size_t)(k0 + kk) * N + bn + n4);
        }
        __syncthreads();
#pragma unroll
        for (int k = 0; k < 16; ++k) {
            float a[TM], b[TN];
#pragma unroll
            for (int i = 0; i < TM / 4; ++i)
                *(float4*)&a[i * 4] = *(const float4*)&As[k][ty * TM + i * 4];
            *(float4*)&b[0] = *(const float4*)&Bs[k][tx * 4];
            *(float4*)&b[4] = *(const float4*)&Bs[k][BN / 2 + tx * 4];
#pragma unroll
            for (int i = 0; i < TM; ++i)
#pragma unroll
                for (int j = 0; j < TN; ++j) acc[i][j] += a[i] * b[j];
        }
        __syncthreads();
    }

    float bv[8] = {0, 0, 0, 0, 0, 0, 0, 0};
    if (bias) {
#pragma unroll
        for (int j = 0; j < 4; ++j) {
            bv[j]     = bias[bn + tx * 4 + j];
            bv[4 + j] = bias[bn + BN / 2 + tx * 4 + j];
        }
    }
#pragma unroll
    for (int i = 0; i < TM; ++i) {
        int row = bm + ty * TM + i;
        float4 o0 = make_float4(acc[i][0] + bv[0], acc[i][1] + bv[1],
                                acc[i][2] + bv[2], acc[i][3] + bv[3]);
        float4 o1 = make_float4(acc[i][4] + bv[4], acc[i][5] + bv[5],
                                acc[i][6] + bv[6], acc[i][7] + bv[7]);
        *(float4*)(C + (size_t)row * N + bn + tx * 4) = o0;
        *(float4*)(C + (size_t)row * N + bn + BN / 2 + tx * 4) = o1;
    }
}

// ---------------------------------------------------------------------------
// Split-K skinny GEMM (M=64), phase B. 16 slices x K=128:
// slices 0..7 -> (A1,W1), koff=p*128 ; 8..15 -> (A2,W2), koff=(p-8)*128.
// Tile 64x256, thread-tile 8x8.
// ---------------------------------------------------------------------------
__global__ __launch_bounds__(256) void bgemm(
    const float* __restrict__ A1, int lda1,
    const float* __restrict__ A2, int lda2,
    const float* __restrict__ W1, const float* __restrict__ W2, int ldw,
    float* __restrict__ part, int Ntot, int p_off)
{
    __shared__ float As[16][64];
    __shared__ float Ws[16][256];

    const int t  = threadIdx.x;
    const int bn = blockIdx.x * 256;
    const int p  = blockIdx.y + p_off;

    const float* A; const float* W; int lda; int koff;
    if (p < 8) { A = A1; lda = lda1; W = W1; koff = p * 128; }
    else       { A = A2; lda = lda2; W = W2; koff = (p - 8) * 128; }

    const int tx = t & 31;
    const int ty = t >> 5;

    float acc[8][8];
#pragma unroll
    for (int i = 0; i < 8; ++i)
#pragma unroll
        for (int j = 0; j < 8; ++j) acc[i][j] = 0.0f;

    const int am = t >> 2;
    const int ak = (t & 3) * 4;
    const float* Ap = A + (size_t)am * lda + koff + ak;

    for (int kc = 0; kc < 128; kc += 16) {
        float4 av = *(const float4*)(Ap + kc);
        As[ak + 0][am] = av.x; As[ak + 1][am] = av.y;
        As[ak + 2][am] = av.z; As[ak + 3][am] = av.w;
#pragma unroll
        for (int j = 0; j < 4; ++j) {
            int flat = t + 256 * j;
            int kk = flat >> 6;
            int n4 = (flat & 63) * 4;
            *(float4*)&Ws[kk][n4] =
                *(const float4*)(W + (size_t)(koff + kc + kk) * ldw + bn + n4);
        }
        __syncthreads();
#pragma unroll
        for (int k = 0; k < 16; ++k) {
            float a[8], b[8];
            *(float4*)&a[0] = *(const float4*)&As[k][ty * 8];
            *(float4*)&a[4] = *(const float4*)&As[k][ty * 8 + 4];
            *(float4*)&b[0] = *(const float4*)&Ws[k][tx * 4];
            *(float4*)&b[4] = *(const float4*)&Ws[k][128 + tx * 4];
#pragma unroll
            for (int i = 0; i < 8; ++i)
#pragma unroll
                for (int j = 0; j < 8; ++j) acc[i][j] += a[i] * b[j];
        }
        __syncthreads();
    }

    float* outp = part + (size_t)p * 64 * Ntot + bn;
#pragma unroll
    for (int i = 0; i < 8; ++i) {
        int row = ty * 8 + i;
        *(float4*)(outp + (size_t)row * Ntot + tx * 4) =
            make_float4(acc[i][0], acc[i][1], acc[i][2], acc[i][3]);
        *(float4*)(outp + (size_t)row * Ntot + 128 + tx * 4) =
            make_float4(acc[i][4], acc[i][5], acc[i][6], acc[i][7]);
    }
}

// ---------------------------------------------------------------------------
// Reduce gate partials + optional additive term + bias, LSTM update.
// ---------------------------------------------------------------------------
__global__ __launch_bounds__(256) void lstm_k(
    const float* __restrict__ part, int pbase,
    const float* __restrict__ addin, int adstride,
    const float* __restrict__ bias,
    const float* __restrict__ cin, float* __restrict__ cout,
    float* __restrict__ hout)
{
    int idx = blockIdx.x * 256 + threadIdx.x;
    int b = idx >> 10;
    int h = idx & 1023;
    float zi = 0, zf = 0, zg = 0, zo = 0;
    for (int p = pbase; p < 16; ++p) {
        const float* q = part + (size_t)p * 64 * 4096 + b * 4096 + h;
        zi += q[0]; zf += q[1024]; zg += q[2048]; zo += q[3072];
    }
    if (addin) {
        const float* a = addin + (size_t)b * adstride + h;
        zi += a[0]; zf += a[1024]; zg += a[2048]; zo += a[3072];
    }
    if (bias) {
        zi += bias[h]; zf += bias[1024 + h];
        zg += bias[2048 + h]; zo += bias[3072 + h];
    }
    float cc = sigm(zf) * cin[idx] + sigm(zi) * tanhf(zg);
    cout[idx] = cc;
    hout[idx] = sigm(zo) * tanhf(cc);
}

// ---------------------------------------------------------------------------
// Per-b block: reduce q partials (8 slices), Bahdanau scores, softmax, ctx.
// ---------------------------------------------------------------------------
__global__ __launch_bounds__(256) void attn_k(
    const float* __restrict__ qpart, const float* __restrict__ keys,
    const float* __restrict__ vvec, const float* __restrict__ mem,
    float* __restrict__ ctx)
{
    __shared__ float q_lds[1024];
    __shared__ float v_lds[1024];
    __shared__ float s_lds[64];
    const int b = blockIdx.x;
    const int t = threadIdx.x;

#pragma unroll
    for (int j = 0; j < 4; ++j) {
        int u = t + 256 * j;
        float acc = 0;
#pragma unroll
        for (int p = 0; p < 8; ++p) acc += qpart[(size_t)p * 65536 + b * 1024 + u];
        q_lds[u] = acc;
        v_lds[u] = vvec[u];
    }
    __syncthreads();

    const int s = t >> 2;
    const int uq = t & 3;
    const float* krow = keys + (size_t)b * (Ssz * Hsz) + s * Hsz;
    float sc = 0;
    for (int i = 0; i < 64; ++i) {
        int u = i * 16 + uq * 4;
        float4 kv = *(const float4*)(krow + u);
        sc += v_lds[u + 0] * tanhf(kv.x + q_lds[u + 0]);
        sc += v_lds[u + 1] * tanhf(kv.y + q_lds[u + 1]);
        sc += v_lds[u + 2] * tanhf(kv.z + q_lds[u + 2]);
        sc += v_lds[u + 3] * tanhf(kv.w + q_lds[u + 3]);
    }
    sc += __shfl_xor(sc, 1);
    sc += __shfl_xor(sc, 2);
    if (uq == 0) s_lds[s] = sc;
    __syncthreads();

    if (t < 64) {
        float x = s_lds[t];
        float mx = x;
        for (int d = 1; d < 64; d <<= 1) mx = fmaxf(mx, __shfl_xor(mx, d));
        float e = __expf(x - mx);
        float sm = e;
        for (int d = 1; d < 64; d <<= 1) sm += __shfl_xor(sm, d);
        s_lds[t] = e / sm;
    }
    __syncthreads();

#pragma unroll
    for (int j = 0; j < 4; ++j) {
        int m = t + 256 * j;
        float acc = 0;
        for (int s2 = 0; s2 < 64; ++s2)
            acc += s_lds[s2] * mem[(size_t)b * (Ssz * Hsz) + s2 * Hsz + m];
        ctx[b * 1024 + m] = acc;
    }
}

// Sum 16 attn-proj partials -> outs[:, tstep, :] (+ bf16 hi/lo for phase C)
__global__ __launch_bounds__(256) void radd(
    const float* __restrict__ part, float* __restrict__ outs,
    __hip_bfloat16* __restrict__ ahi, __hip_bfloat16* __restrict__ alo,
    int tstep)
{
    int idx = blockIdx.x * 256 + threadIdx.x;
    int b = idx >> 10;
    int n = idx & 1023;
    float acc = 0;
#pragma unroll
    for (int p = 0; p < 16; ++p) acc += part[(size_t)p * 65536 + idx];
    size_t o = ((size_t)b * Tsz + tstep) * Hsz + n;
    outs[o] = acc;
    __hip_bfloat16 hi = __float2bfloat16(acc);
    ahi[o] = hi;
    alo[o] = __float2bfloat16(acc - __bfloat162float(hi));
}

// ---------------------------------------------------------------------------
// Transpose + hi/lo split of a 1024 x 16000 column-slab of Wfc into
// whiT/wloT [16000][1024] bf16.
// ---------------------------------------------------------------------------
__global__ __launch_bounds__(256) void splitT_k(
    const float* __restrict__ Wfc, int colbase,
    __hip_bfloat16* __restrict__ whiT, __hip_bfloat16* __restrict__ wloT)
{
    __shared__ float tile[64][65];
    const int t  = threadIdx.x;
    const int kt = blockIdx.x & 15;   // 16 k-tiles of 64
    const int nt = blockIdx.x >> 4;   // 250 n-tiles of 64
    const int kb = kt * 64;
    const int nb = nt * 64;
#pragma unroll
    for (int it = 0; it < 16; ++it) {
        int idx = it * 256 + t;
        int r = idx >> 6, c = idx & 63;
        tile[r][c] = Wfc[(size_t)(kb + r) * Vsz + colbase + nb + c];
    }
    __syncthreads();
#pragma unroll
    for (int it = 0; it < 16; ++it) {
        int idx = it * 256 + t;
        int r2 = idx >> 6, c2 = idx & 63;
        float v = tile[c2][r2];
        __hip_bfloat16 hi = __float2bfloat16(v);
        __hip_bfloat16 lo = __float2bfloat16(v - __bfloat162float(hi));
        size_t o = (size_t)(nb + r2) * 1024 + kb + c2;
        whiT[o] = hi;
        wloT[o] = lo;
    }
}

// ---------------------------------------------------------------------------
// Phase C MFMA GEMM: out[2048, colbase+16000 slab] = A @ W + bfc
// A = ahi+alo [2048][1024] bf16, W^T = whiT+wloT [16000][1024] bf16.
// 3-pass: Ahi*Whi + Alo*Whi + Ahi*Wlo. 128x128 tile, BK=32, 4 waves (2x2),
// each wave 64x64 via 2x2 frags of mfma_f32_32x32x16_bf16.
// LDS: 4 tiles [128 rows][32 k] bf16 (64B rows, 4x 16B chunks).
// Swizzle (write AND read): phys_chunk = logical_chunk ^ ((row>>1)&3).
// Bank check: byte = row*64 + phys*16 -> rows 0..7 cover all 32 banks exactly
// once on both ds_write_b128 and frag ds_read_b128 (2-way max = free, m136).
// Staging is register-staged (load dwordx4 -> ds_write_b128): the proven-safe
// instruction class from round-1's passing kernels.
// ---------------------------------------------------------------------------
__global__ __launch_bounds__(256) void mfmaC_k(
    const __hip_bfloat16* __restrict__ ahi, const __hip_bfloat16* __restrict__ alo,
    const __hip_bfloat16* __restrict__ whiT, const __hip_bfloat16* __restrict__ wloT,
    const float* __restrict__ bfc, float* __restrict__ out, int colbase)
{
    __shared__ __align__(16) unsigned short smem[4 * 4096];  // AH, AL, WH, WL

    const int t    = threadIdx.x;
    const int w    = t >> 6;
    const int lane = t & 63;
    const int mt = blockIdx.x & 15;   // 16 M-tiles; consecutive blocks share W panel
    const int nt = blockIdx.x >> 4;   // 125 N-tiles
    const int bm = mt * 128;
    const int bn = nt * 128;

    // --- staging: lane covers rows rl0=w*32+(lane>>2), rl1=rl0+16, chunk lane&3.
    // Natural global chunk; ds_write to swizzled phys slot. swst invariant under
    // row+16 (16>>1=8 = 0 mod 4) -> one constant for both rows.
    const int r16 = lane >> 2;
    const int cp  = lane & 3;
    const int rl0 = w * 32 + r16;
    const int rl1 = rl0 + 16;
    const int swst = (rl0 >> 1) & 3;
    const int ps  = (cp ^ swst) * 8;          // phys elem offset within 32-elem row
    const size_t gA0 = (size_t)(bm + rl0) * 1024 + cp * 8;
    const size_t gA1 = (size_t)(bm + rl1) * 1024 + cp * 8;
    const size_t gW0 = (size_t)(bn + rl0) * 1024 + cp * 8;
    const size_t gW1 = (size_t)(bn + rl1) * 1024 + cp * 8;
    const int l0 = rl0 * 32 + ps;             // LDS elem index, row rl0
    const int l1 = rl1 * 32 + ps;

    // --- fragment addressing
    const int wm = w >> 1, wn = w & 1;
    const int fr = lane & 31;                 // A-row / B-col within 32
    const int fh = lane >> 5;                 // k-half selector
    const int swrd = (fr >> 1) & 3;           // read swizzle ((row>>1)&3, wm*64 = 0 mod 4)
    const int arow0 = (wm * 64 + fr) * 32;    // elem offsets (32 elems/row)
    const int arow1 = arow0 + 32 * 32;
    const int nrow0 = (wn * 64 + fr) * 32;
    const int nrow1 = nrow0 + 32 * 32;

    floatx16 acc00 = {}, acc01 = {}, acc10 = {}, acc11 = {};

    for (int k0 = 0; k0 < 1024; k0 += 32) {
        bhalf8 vA0 = *(const bhalf8*)(ahi  + gA0 + k0);
        bhalf8 vA1 = *(const bhalf8*)(ahi  + gA1 + k0);
        bhalf8 vL0 = *(const bhalf8*)(alo  + gA0 + k0);
        bhalf8 vL1 = *(const bhalf8*)(alo  + gA1 + k0);
        bhalf8 vW0 = *(const bhalf8*)(whiT + gW0 + k0);
        bhalf8 vW1 = *(const bhalf8*)(whiT + gW1 + k0);
        bhalf8 vX0 = *(const bhalf8*)(wloT + gW0 + k0);
        bhalf8 vX1 = *(const bhalf8*)(wloT + gW1 + k0);
        *(bhalf8*)&smem[l0]          = vA0;
        *(bhalf8*)&smem[l1]          = vA1;
        *(bhalf8*)&smem[4096 + l0]   = vL0;
        *(bhalf8*)&smem[4096 + l1]   = vL1;
        *(bhalf8*)&smem[8192 + l0]   = vW0;
        *(bhalf8*)&smem[8192 + l1]   = vW1;
        *(bhalf8*)&smem[12288 + l0]  = vX0;
        *(bhalf8*)&smem[12288 + l1]  = vX1;
        __syncthreads();

#pragma unroll
        for (int kk = 0; kk < 2; ++kk) {
            const int cpa = ((kk * 2 + fh) ^ swrd) * 8;
            bhalf8 aH0 = *(const bhalf8*)&smem[arow0 + cpa];
            bhalf8 aH1 = *(const bhalf8*)&smem[arow1 + cpa];
            bhalf8 aL0 = *(const bhalf8*)&smem[4096 + arow0 + cpa];
            bhalf8 aL1 = *(const bhalf8*)&smem[4096 + arow1 + cpa];
            bhalf8 bH0 = *(const bhalf8*)&smem[8192 + nrow0 + cpa];
            bhalf8 bH1 = *(const bhalf8*)&smem[8192 + nrow1 + cpa];
            bhalf8 bL0 = *(const bhalf8*)&smem[12288 + nrow0 + cpa];
            bhalf8 bL1 = *(const bhalf8*)&smem[12288 + nrow1 + cpa];

            acc00 = __builtin_amdgcn_mfma_f32_32x32x16_bf16(aH0, bH0, acc00, 0, 0, 0);
            acc01 = __builtin_amdgcn_mfma_f32_32x32x16_bf16(aH0, bH1, acc01, 0, 0, 0);
            acc10 = __builtin_amdgcn_mfma_f32_32x32x16_bf16(aH1, bH0, acc10, 0, 0, 0);
            acc11 = __builtin_amdgcn_mfma_f32_32x32x16_bf16(aH1, bH1, acc11, 0, 0, 0);
            acc00 = __builtin_amdgcn_mfma_f32_32x32x16_bf16(aL0, bH0, acc00, 0, 0, 0);
            acc01 = __builtin_amdgcn_mfma_f32_32x32x16_bf16(aL0, bH1, acc01, 0, 0, 0);
            acc10 = __builtin_amdgcn_mfma_f32_32x32x16_bf16(aL1, bH0, acc10, 0, 0, 0);
            acc11 = __builtin_amdgcn_mfma_f32_32x32x16_bf16(aL1, bH1, acc11, 0, 0, 0);
            acc00 = __builtin_amdgcn_mfma_f32_32x32x16_bf16(aH0, bL0, acc00, 0, 0, 0);
            acc01 = __builtin_amdgcn_mfma_f32_32x32x16_bf16(aH0, bL1, acc01, 0, 0, 0);
            acc10 = __builtin_amdgcn_mfma_f32_32x32x16_bf16(aH1, bL0, acc10, 0, 0, 0);
            acc11 = __builtin_amdgcn_mfma_f32_32x32x16_bf16(aH1, bL1, acc11, 0, 0, 0);
        }
        __syncthreads();
    }

    // epilogue: C/D layout col=lane&31, row=(reg&3)+8*(reg>>2)+4*(lane>>5)
    const int colg = colbase + bn + wn * 64 + fr;
    const float bv0 = bfc[colg];
    const float bv1 = bfc[colg + 32];
#pragma unroll
    for (int r = 0; r < 16; ++r) {
        int rrow = (r & 3) + 8 * (r >> 2) + 4 * fh;
        size_t row0 = (size_t)(bm + wm * 64 + rrow) * Vsz + colg;
        size_t row1 = row0 + (size_t)32 * Vsz;
        out[row0]      = acc00[r] + bv0;
        out[row0 + 32] = acc01[r] + bv1;
        out[row1]      = acc10[r] + bv0;
        out[row1 + 32] = acc11[r] + bv1;
    }
}

// ---------------------------------------------------------------------------
extern "C" void kernel_launch(void* const* d_in, const int* in_sizes, int n_in,
                              void* d_out, int out_size, void* d_ws, size_t ws_size,
                              hipStream_t stream)
{
    (void)in_sizes; (void)n_in; (void)out_size; (void)ws_size;
    const int*   tokens = (const int*)  d_in[0];
    const float* memory = (const float*)d_in[1];
    const float* enc_h  = (const float*)d_in[2];
    const float* enc_c  = (const float*)d_in[3];
    const float* emb    = (const float*)d_in[4];
    const float* k0     = (const float*)d_in[5];
    const float* r0     = (const float*)d_in[6];
    const float* b0     = (const float*)d_in[7];
    const float* k1     = (const float*)d_in[8];
    const float* r1     = (const float*)d_in[9];
    const float* b1     = (const float*)d_in[10];
    const float* Wq     = (const float*)d_in[11];
    const float* Wk     = (const float*)d_in[12];
    const float* vvec   = (const float*)d_in[13];
    const float* Wa     = (const float*)d_in[14];
    const float* Wfc    = (const float*)d_in[15];
    const float* bfc    = (const float*)d_in[16];
    float* out = (float*)d_out;

    // --- persistent region (live across phases): 17.25 MB
    char* wb = (char*)d_ws;
    float* outs = (float*)wb; wb += (size_t)2048 * 1024 * 4;
    float* h0   = (float*)wb; wb += 65536 * 4;
    float* c0   = (float*)wb; wb += 65536 * 4;
    float* h1   = (float*)wb; wb += 65536 * 4;
    float* c1   = (float*)wb; wb += 65536 * 4;
    float* ctxb = (float*)wb; wb += 65536 * 4;
    __hip_bfloat16* ahi = (__hip_bfloat16*)wb; wb += (size_t)2048 * 1024 * 2;
    __hip_bfloat16* alo = (__hip_bfloat16*)wb; wb += (size_t)2048 * 1024 * 2;

    // --- scratch region: AB view (~71 MB) unioned with C view (~65.5 MB)
    char* scr = wb;
    float* xk   = (float*)scr;
    float* keys = (float*)(scr + (size_t)2048 * 4096 * 4);
    float* gp   = (float*)(scr + (size_t)(2048 * 4096 + 4096 * 1024) * 4);
    float* qp   = (float*)(scr + (size_t)(2048 * 4096 + 4096 * 1024 + 16 * 64 * 4096) * 4);
    float* ap   = (float*)(scr + (size_t)(2048 * 4096 + 4096 * 1024 + 16 * 64 * 4096 + 8 * 65536) * 4);
    __hip_bfloat16* whiT = (__hip_bfloat16*)scr;                               // phase C only
    __hip_bfloat16* wloT = (__hip_bfloat16*)(scr + (size_t)16000 * 1024 * 2);  // phase C only

    // Phase A
    gemm_t<128, 256, 16, 8><<<dim3(16, 16), 256, 0, stream>>>(
        emb, k0, b0, tokens, xk, 2048, 4096, Esz, Esz);
    gemm_t<128, 128, 8, 8><<<dim3(32, 8), 256, 0, stream>>>(
        memory, Wk, nullptr, nullptr, keys, 4096, 1024, 1024, 1024);

    const float* k0a = k0 + (size_t)Esz * 4096;

    for (int t = 0; t < Tsz; ++t) {
        const float* a_prev = outs + (size_t)(t - 1) * Hsz;
        const float* h0_in = (t == 0) ? enc_h : h0;
        const float* h1_in = (t == 0) ? enc_h : h1;
        const float* c0_in = (t == 0) ? enc_c : c0;
        const float* c1_in = (t == 0) ? enc_c : c1;

        // gates0: [attn_prev | h0_in] @ [k0a ; r0]  (t=0: attn=0 -> h0 side only)
        if (t == 0)
            bgemm<<<dim3(16, 8), 256, 0, stream>>>(
                nullptr, 0, h0_in, 1024, k0a, r0, 4096, gp, 4096, 8);
        else
            bgemm<<<dim3(16, 16), 256, 0, stream>>>(
                a_prev, Tsz * Hsz, h0_in, 1024, k0a, r0, 4096, gp, 4096, 0);
        lstm_k<<<256, 256, 0, stream>>>(
            gp, (t == 0) ? 8 : 0, xk + (size_t)t * 4096, Tsz * 4096,
            nullptr, c0_in, c0, h0);
        // gates1: [h0 | h1_in] @ [k1 ; r1]
        bgemm<<<dim3(16, 16), 256, 0, stream>>>(
            h0, 1024, h1_in, 1024, k1, r1, 4096, gp, 4096, 0);
        lstm_k<<<256, 256, 0, stream>>>(
            gp, 0, nullptr, 0, b1, c1_in, c1, h1);
        // q: h1 @ Wq (K=1024 -> 8 slices, A1 side only)
        bgemm<<<dim3(4, 8), 256, 0, stream>>>(
            h1, 1024, nullptr, 0, Wq, nullptr, 1024, qp, 1024, 0);
        attn_k<<<64, 256, 0, stream>>>(qp, keys, vvec, memory, ctxb);
        // attn-proj: [h1 | ctx] @ Wa
        bgemm<<<dim3(4, 16), 256, 0, stream>>>(
            h1, 1024, ctxb, 1024, Wa, Wa + (size_t)1024 * 1024, 1024, ap, 1024, 0);
        radd<<<256, 256, 0, stream>>>(ap, outs, ahi, alo, t);
    }

    // Phase C in two 16000-column halves (scratch overlays phase-AB buffers)
    for (int h = 0; h < 2; ++h) {
        splitT_k<<<4000, 256, 0, stream>>>(Wfc, h * 16000, whiT, wloT);
        mfmaC_k<<<2000, 256, 0, stream>>>(ahi, alo, whiT, wloT, bfc, out, h * 16000);
    }
}